// Round 1
// 1777.324 us; speedup vs baseline: 3.1786x; 3.1786x over previous
//
#include <hip/hip_runtime.h>
#include <math.h>

#define LAYERS 2
#define NNEI 120
#define NPAD 128
#define ED 64
#define HD 128
#define NB 4096
#define F3 (3*HD)
#define SCALING 0.088388347648318447f
#define LN_EPS 1e-5f
#define T 512
#define XPAD 68
#define QPAD 136

typedef unsigned short u16;
typedef unsigned int u32;
typedef unsigned char u8;
typedef float f32x4 __attribute__((ext_vector_type(4)));
typedef short bf16x8 __attribute__((ext_vector_type(8)));

__device__ __forceinline__ float bf2f(u16 u) { return __uint_as_float(((u32)u) << 16); }
__device__ __forceinline__ u16 f2bf(float f) {
  u32 i = __float_as_uint(f);
  u32 r = (i + 0x7fffu + ((i >> 16) & 1u)) >> 16;   // RNE
  return (u16)r;
}

template<bool F32>
__device__ __forceinline__ float gld(const void* p, long i) {
  if constexpr (F32) return ((const float*)p)[i];
  else               return bf2f(((const u16*)p)[i]);
}
template<bool MBYTE>
__device__ __forceinline__ int mld(const void* p, long i) {
  if constexpr (MBYTE) return (int)((const u8*)p)[i];
  else                 return ((const int*)p)[i];
}

__device__ __forceinline__ float red16sum(float v) {
  v += __shfl_xor(v, 1); v += __shfl_xor(v, 2);
  v += __shfl_xor(v, 4); v += __shfl_xor(v, 8);
  return v;
}
__device__ __forceinline__ float red16max(float v) {
  v = fmaxf(v, __shfl_xor(v, 1)); v = fmaxf(v, __shfl_xor(v, 2));
  v = fmaxf(v, __shfl_xor(v, 4)); v = fmaxf(v, __shfl_xor(v, 8));
  return v;
}

#define MFMA(a, b, d) (d) = __builtin_amdgcn_mfma_f32_16x16x32_bf16((a), (b), (d), 0, 0, 0)

// ---- detector: flags[0]=1 if float inputs are f32; flags[1]=1 if mask is byte ----
__global__ void detect_kernel(const u16* __restrict__ G,
                              const u8* __restrict__ mask,
                              int* __restrict__ flags) {
  if (threadIdx.x == 0 && blockIdx.x == 0) {
    int isf32 = 0;
    for (int i = 0; i < 256; ++i) {
      int e = (G[2 * i] >> 7) & 0xff;
      if (e >= 150) { isf32 = 1; break; }
    }
    int mbyte = 0;
    for (int i = 1; i < 4096; ++i) {
      if ((i & 3) && mask[i]) { mbyte = 1; break; }
    }
    flags[0] = isf32;
    flags[1] = mbyte;
  }
}

// ---- prep: transpose + hi/lo bf16-split weights into workspace ----
// wT[l][f][e] (hi/lo), owT[l][e][h] (hi/lo)
__global__ void prep_kernel(const void* __restrict__ in_w, const void* __restrict__ out_w,
                            u16* __restrict__ wt_hi, u16* __restrict__ wt_lo,
                            u16* __restrict__ ow_hi, u16* __restrict__ ow_lo,
                            const int* __restrict__ flags) {
  const bool f32 = flags[0] != 0;
  const int i = blockIdx.x * blockDim.x + threadIdx.x;
  if (i < LAYERS * F3 * ED) {
    const int l = i / (F3 * ED);
    const int rem = i % (F3 * ED);
    const int f = rem / ED;
    const int e = rem % ED;
    const long src = (long)(l * ED + e) * F3 + f;
    const float w = f32 ? ((const float*)in_w)[src] : bf2f(((const u16*)in_w)[src]);
    const u16 h = f2bf(w);
    wt_hi[i] = h;
    wt_lo[i] = f2bf(w - bf2f(h));
  }
  if (i < LAYERS * ED * HD) {
    const int l = i / (ED * HD);
    const int rem = i % (ED * HD);
    const int e = rem / HD;
    const int hh = rem % HD;
    const long src = (long)(l * HD + hh) * ED + e;
    const float w = f32 ? ((const float*)out_w)[src] : bf2f(((const u16*)out_w)[src]);
    const u16 h = f2bf(w);
    ow_hi[i] = h;
    ow_lo[i] = f2bf(w - bf2f(h));
  }
}

template<bool F32, bool MBYTE>
__global__ __launch_bounds__(T, 2) void nwa_kernel(
    const void* __restrict__ G, const void* __restrict__ mask,
    const void* __restrict__ rr,
    const void* __restrict__ in_b, const void* __restrict__ out_b,
    const void* __restrict__ ln_g, const void* __restrict__ ln_b,
    const u16* __restrict__ wt_hi, const u16* __restrict__ wt_lo,
    const u16* __restrict__ ow_hi, const u16* __restrict__ ow_lo,
    void* __restrict__ out, const int* __restrict__ flags)
{
  if (((flags[0] != 0) != F32) || ((flags[1] != 0) != MBYTE)) return;

  __shared__ __align__(16) float x_s[NPAD][XPAD];   // f32 x / residual (rows 120..127 zero)
  __shared__ __align__(16) u16 q_s[NPAD][QPAD];     // q, then aw (per-wave row band)
  __shared__ __align__(16) u16 k_s[NPAD][QPAD];     // k, then o
  __shared__ __align__(16) u16 vT_s[HD][QPAD];      // v transposed: [h][m]
  __shared__ __align__(16) float r_s[NPAD][4];
  __shared__ int m_s[NPAD];

  const int b = blockIdx.x;
  const int t = threadIdx.x;
  const int wave = t >> 6;
  const int lane = t & 63;
  const int g = lane >> 4;     // K-group / D-row group
  const int c = lane & 15;     // A-row / B-col / D-col within 16-tile

  // ---- load x, r, mask; zero pads ----
  {
    const long gbase = (long)b * (NNEI * ED);
    for (int i = t; i < NNEI * ED; i += T)
      x_s[i >> 6][i & 63] = gld<F32>(G, gbase + i);
    for (int i = t; i < (NPAD - NNEI) * ED; i += T)
      x_s[NNEI + (i >> 6)][i & 63] = 0.f;
    const long rbase = (long)b * (NNEI * 3);
    const long mbase = (long)b * NNEI;
    for (int i = t; i < NPAD; i += T) {
      if (i < NNEI) {
        r_s[i][0] = gld<F32>(rr, rbase + i * 3 + 0);
        r_s[i][1] = gld<F32>(rr, rbase + i * 3 + 1);
        r_s[i][2] = gld<F32>(rr, rbase + i * 3 + 2);
        r_s[i][3] = 0.f;
        m_s[i] = mld<MBYTE>(mask, mbase + i);
      } else {
        r_s[i][0] = 0.f; r_s[i][1] = 0.f; r_s[i][2] = 0.f; r_s[i][3] = 0.f;
        m_s[i] = 0;
      }
    }
  }
  __syncthreads();

  // per-lane masks (constant across layers)
  int vmask = 0;
  #pragma unroll
  for (int mt = 0; mt < 8; ++mt) vmask |= (m_s[16 * mt + c] ? 1 : 0) << mt;
  float qmr[4];
  #pragma unroll
  for (int r = 0; r < 4; ++r) qmr[r] = m_s[16 * wave + 4 * g + r] ? 1.f : 0.f;

  for (int l = 0; l < LAYERS; ++l) {
    __syncthreads();   // barrier A: prev-layer vT reads done before new v writes

    // ---- phase 1: qkv = x @ in_w + in_b (MFMA, x and w hi/lo split); l2norm; store ----
    {
      const long wofs = (long)l * (F3 * ED);
      const long bbase = (long)l * F3;
      bf16x8 a_hi[2], a_lo[2];
      #pragma unroll
      for (int kf = 0; kf < 2; ++kf) {
        const float* xp = &x_s[16 * wave + c][32 * kf + 8 * g];
        float af[8];
        *(f32x4*)&af[0] = *(const f32x4*)xp;
        *(f32x4*)&af[4] = *(const f32x4*)(xp + 4);
        #pragma unroll
        for (int j = 0; j < 8; ++j) {
          const u16 h = f2bf(af[j]);
          a_hi[kf][j] = (short)h;
          a_lo[kf][j] = (short)f2bf(af[j] - bf2f(h));
        }
      }
      #pragma unroll
      for (int grp = 0; grp < 3; ++grp) {
        f32x4 acc[8];
        #pragma unroll
        for (int nt = 0; nt < 8; ++nt) {
          const int fcol = grp * 128 + nt * 16 + c;
          const u16* bph = wt_hi + wofs + (long)fcol * ED + 8 * g;
          const u16* bpl = wt_lo + wofs + (long)fcol * ED + 8 * g;
          const bf16x8 bh0 = *(const bf16x8*)bph;
          const bf16x8 bh1 = *(const bf16x8*)(bph + 32);
          const bf16x8 bl0 = *(const bf16x8*)bpl;
          const bf16x8 bl1 = *(const bf16x8*)(bpl + 32);
          f32x4 d = {0.f, 0.f, 0.f, 0.f};
          MFMA(a_hi[0], bh0, d);
          MFMA(a_hi[1], bh1, d);
          MFMA(a_lo[0], bh0, d);
          MFMA(a_lo[1], bh1, d);
          MFMA(a_hi[0], bl0, d);
          MFMA(a_hi[1], bl1, d);
          const float bias = gld<F32>(in_b, bbase + fcol);
          acc[nt][0] = d[0] + bias; acc[nt][1] = d[1] + bias;
          acc[nt][2] = d[2] + bias; acc[nt][3] = d[3] + bias;
        }
        float inv[4];
        #pragma unroll
        for (int r = 0; r < 4; ++r) {
          float ss = 0.f;
          #pragma unroll
          for (int nt = 0; nt < 8; ++nt) ss += acc[nt][r] * acc[nt][r];
          ss = red16sum(ss);
          inv[r] = 1.f / fmaxf(sqrtf(ss), 1e-12f);
          if (grp == 0) inv[r] *= SCALING;
        }
        if (grp < 2) {
          u16 (*dst)[QPAD] = (grp == 0) ? q_s : k_s;
          #pragma unroll
          for (int nt = 0; nt < 8; ++nt) {
            #pragma unroll
            for (int r = 0; r < 4; ++r)
              dst[16 * wave + 4 * g + r][16 * nt + c] = f2bf(acc[nt][r] * inv[r]);
          }
        } else {
          #pragma unroll
          for (int nt = 0; nt < 8; ++nt) {
            const u32 p01 = (u32)f2bf(acc[nt][0] * inv[0]) | ((u32)f2bf(acc[nt][1] * inv[1]) << 16);
            const u32 p23 = (u32)f2bf(acc[nt][2] * inv[2]) | ((u32)f2bf(acc[nt][3] * inv[3]) << 16);
            *(u32*)&vT_s[16 * nt + c][16 * wave + 4 * g + 0] = p01;
            *(u32*)&vT_s[16 * nt + c][16 * wave + 4 * g + 2] = p23;
          }
        }
      }
    }
    __syncthreads();   // barrier B: q/k/vT visible to all waves

    // ---- QK^T (S = q @ k^T) ----
    f32x4 s[8];
    {
      bf16x8 aq[4];
      #pragma unroll
      for (int kf = 0; kf < 4; ++kf)
        aq[kf] = *(const bf16x8*)&q_s[16 * wave + c][32 * kf + 8 * g];
      #pragma unroll
      for (int mt = 0; mt < 8; ++mt) {
        const u16* kp = &k_s[16 * mt + c][8 * g];
        f32x4 d = {0.f, 0.f, 0.f, 0.f};
        #pragma unroll
        for (int kf = 0; kf < 4; ++kf)
          MFMA(aq[kf], *(const bf16x8*)(kp + 32 * kf), d);
        s[mt] = d;
      }
    }

    // ---- softmax + mask_q + ang; aw -> q_s (own row band only) ----
    {
      const f32x4 minf = {-INFINITY, -INFINITY, -INFINITY, -INFINITY};
      #pragma unroll
      for (int mt = 0; mt < 8; ++mt)
        if (!((vmask >> mt) & 1)) s[mt] = minf;
      float inv[4];
      float4 rnr[4];
      #pragma unroll
      for (int r = 0; r < 4; ++r) {
        float mx = s[0][r];
        #pragma unroll
        for (int mt = 1; mt < 8; ++mt) mx = fmaxf(mx, s[mt][r]);
        mx = red16max(mx);
        float sm = 0.f;
        #pragma unroll
        for (int mt = 0; mt < 8; ++mt) {
          const float e = __expf(s[mt][r] - mx);   // masked: exp(-inf)=0
          s[mt][r] = e;
          sm += e;
        }
        sm = red16sum(sm);
        inv[r] = qmr[r] / sm;                       // fold mask_q in
        rnr[r] = *(const float4*)&r_s[16 * wave + 4 * g + r][0];
      }
      #pragma unroll
      for (int mt = 0; mt < 8; ++mt) {
        const float4 rm = *(const float4*)&r_s[16 * mt + c][0];
        #pragma unroll
        for (int r = 0; r < 4; ++r) {
          const float w = s[mt][r] * inv[r] *
              (rnr[r].x * rm.x + rnr[r].y * rm.y + rnr[r].z * rm.z);
          q_s[16 * wave + 4 * g + r][16 * mt + c] = f2bf(w);
        }
      }
    }
    __syncthreads();   // barrier C: all k_s reads done; aw visible

    // ---- PV (o = aw @ v) ----
    {
      bf16x8 pa[4];
      #pragma unroll
      for (int kf = 0; kf < 4; ++kf)
        pa[kf] = *(const bf16x8*)&q_s[16 * wave + c][32 * kf + 8 * g];
      f32x4 o[8];
      #pragma unroll
      for (int ht = 0; ht < 8; ++ht) {
        const u16* vp = &vT_s[16 * ht + c][8 * g];
        f32x4 d = {0.f, 0.f, 0.f, 0.f};
        #pragma unroll
        for (int kf = 0; kf < 4; ++kf)
          MFMA(pa[kf], *(const bf16x8*)(vp + 32 * kf), d);
        o[ht] = d;
      }
      #pragma unroll
      for (int ht = 0; ht < 8; ++ht) {
        #pragma unroll
        for (int r = 0; r < 4; ++r)
          k_s[16 * wave + 4 * g + r][16 * ht + c] = f2bf(o[ht][r]);   // o -> k_s
      }
    }
    __syncthreads();   // barrier D: o visible

    // ---- phase 4: x = LN(residual + o @ out_w + out_b) ----
    {
      const long oofs = (long)l * (ED * HD);
      bf16x8 ao[4];
      #pragma unroll
      for (int kf = 0; kf < 4; ++kf)
        ao[kf] = *(const bf16x8*)&k_s[16 * wave + c][32 * kf + 8 * g];
      f32x4 dv[4];
      #pragma unroll
      for (int nt = 0; nt < 4; ++nt) {
        const int e = nt * 16 + c;
        const u16* bph = ow_hi + oofs + (long)e * HD + 8 * g;
        const u16* bpl = ow_lo + oofs + (long)e * HD + 8 * g;
        f32x4 d = {0.f, 0.f, 0.f, 0.f};
        #pragma unroll
        for (int kf = 0; kf < 4; ++kf) {
          MFMA(ao[kf], *(const bf16x8*)(bph + 32 * kf), d);
          MFMA(ao[kf], *(const bf16x8*)(bpl + 32 * kf), d);
        }
        const float ob = gld<F32>(out_b, (long)l * ED + e);
        #pragma unroll
        for (int r = 0; r < 4; ++r)
          dv[nt][r] = d[r] + ob + x_s[16 * wave + 4 * g + r][e];
      }
      float gg[4], bbv[4];
      #pragma unroll
      for (int nt = 0; nt < 4; ++nt) {
        gg[nt]  = gld<F32>(ln_g, (long)l * ED + nt * 16 + c);
        bbv[nt] = gld<F32>(ln_b, (long)l * ED + nt * 16 + c);
      }
      #pragma unroll
      for (int r = 0; r < 4; ++r) {
        const int n = 16 * wave + 4 * g + r;
        float mu = dv[0][r] + dv[1][r] + dv[2][r] + dv[3][r];
        mu = red16sum(mu) * (1.f / 64.f);
        float var = 0.f;
        #pragma unroll
        for (int nt = 0; nt < 4; ++nt) { const float dd = dv[nt][r] - mu; var += dd * dd; }
        var = red16sum(var) * (1.f / 64.f);
        const float rs = rsqrtf(var + LN_EPS);
        if (n < NNEI) {
          #pragma unroll
          for (int nt = 0; nt < 4; ++nt) {
            const float y = (dv[nt][r] - mu) * rs * gg[nt] + bbv[nt];
            x_s[n][nt * 16 + c] = y;
            if (l == LAYERS - 1) {
              const long oidx = (long)b * (NNEI * ED) + (long)n * ED + nt * 16 + c;
              if constexpr (F32) ((float*)out)[oidx] = y;
              else               ((u16*)out)[oidx] = f2bf(y);
            }
          }
        }
      }
    }
  }
}

extern "C" void kernel_launch(void* const* d_in, const int* in_sizes, int n_in,
                              void* d_out, int out_size, void* d_ws, size_t ws_size,
                              hipStream_t stream) {
  (void)in_sizes; (void)n_in; (void)out_size; (void)ws_size;
  const void* G = d_in[0];
  const void* mask = d_in[1];
  const void* rr = d_in[2];
  const void* in_w = d_in[3];
  const void* in_b = d_in[4];
  const void* out_w = d_in[5];
  const void* out_b = d_in[6];
  const void* ln_g = d_in[7];
  const void* ln_b = d_in[8];

  int* flags = (int*)d_ws;
  u16* wt_hi = (u16*)((char*)d_ws + 256);
  u16* wt_lo = wt_hi + LAYERS * F3 * ED;
  u16* ow_hi = wt_lo + LAYERS * F3 * ED;
  u16* ow_lo = ow_hi + LAYERS * ED * HD;

  detect_kernel<<<dim3(1), dim3(64), 0, stream>>>((const u16*)G, (const u8*)mask, flags);
  prep_kernel<<<dim3(96), dim3(T), 0, stream>>>(in_w, out_w, wt_hi, wt_lo, ow_hi, ow_lo, flags);

  nwa_kernel<false, false><<<dim3(NB), dim3(T), 0, stream>>>(
      G, mask, rr, in_b, out_b, ln_g, ln_b, wt_hi, wt_lo, ow_hi, ow_lo, d_out, flags);
  nwa_kernel<false, true><<<dim3(NB), dim3(T), 0, stream>>>(
      G, mask, rr, in_b, out_b, ln_g, ln_b, wt_hi, wt_lo, ow_hi, ow_lo, d_out, flags);
  nwa_kernel<true, false><<<dim3(NB), dim3(T), 0, stream>>>(
      G, mask, rr, in_b, out_b, ln_g, ln_b, wt_hi, wt_lo, ow_hi, ow_lo, d_out, flags);
  nwa_kernel<true, true><<<dim3(NB), dim3(T), 0, stream>>>(
      G, mask, rr, in_b, out_b, ln_g, ln_b, wt_hi, wt_lo, ow_hi, ow_lo, d_out, flags);
}

// Round 2
// 897.056 us; speedup vs baseline: 6.2977x; 1.9813x over previous
//
#include <hip/hip_runtime.h>
#include <math.h>

#define LAYERS 2
#define NNEI 120
#define NPAD 128
#define ED 64
#define HD 128
#define NB 4096
#define F3 (3*HD)
#define SCALING 0.088388347648318447f
#define LN_EPS 1e-5f
#define T 512
#define XP 72
#define QPAD 136

typedef unsigned short u16;
typedef unsigned int u32;
typedef unsigned char u8;
typedef float f32x4 __attribute__((ext_vector_type(4)));
typedef short bf16x8 __attribute__((ext_vector_type(8)));

__device__ __forceinline__ float bf2f(u16 u) { return __uint_as_float(((u32)u) << 16); }
__device__ __forceinline__ u16 f2bf(float f) {
  u32 i = __float_as_uint(f);
  u32 r = (i + 0x7fffu + ((i >> 16) & 1u)) >> 16;   // RNE
  return (u16)r;
}
__device__ __forceinline__ float gldr(const void* p, long i, bool f32) {
  return f32 ? ((const float*)p)[i] : bf2f(((const u16*)p)[i]);
}

__device__ __forceinline__ float red16sum(float v) {
  v += __shfl_xor(v, 1); v += __shfl_xor(v, 2);
  v += __shfl_xor(v, 4); v += __shfl_xor(v, 8);
  return v;
}
__device__ __forceinline__ float red16max(float v) {
  v = fmaxf(v, __shfl_xor(v, 1)); v = fmaxf(v, __shfl_xor(v, 2));
  v = fmaxf(v, __shfl_xor(v, 4)); v = fmaxf(v, __shfl_xor(v, 8));
  return v;
}

#define MFMA(a, b, d) (d) = __builtin_amdgcn_mfma_f32_16x16x32_bf16((a), (b), (d), 0, 0, 0)

__device__ __forceinline__ void gload_lds16(const u16* src, u16* dst) {
  __builtin_amdgcn_global_load_lds(
      (const __attribute__((address_space(1))) u32*)(const void*)src,
      (__attribute__((address_space(3))) u32*)(void*)dst, 16, 0, 0);
}

// Stage a [64 col][64 k] hi+lo weight tile (16 KB) into sbuf.
// LDS layout: row = col (256 B = 16 slots of 16B); slots 0..7 = hi k-chunks,
// 8..15 = lo; stored slot s holds chunk (s&7)^(col&7)  (involution).
// Dest is linear (global_load_lds constraint); source is inverse-swizzled.
__device__ __forceinline__ void stage16(const u16* __restrict__ hi, const u16* __restrict__ lo,
                                        long base, int kstride, u16* sbuf, int wave, int lane) {
  #pragma unroll
  for (int kk = 0; kk < 2; ++kk) {
    const int i = 2 * wave + kk;            // 16 instrs cover 64 cols
    const int col = 4 * i + (lane >> 4);
    const int slot = lane & 15;
    const int chunk = (slot & 7) ^ (col & 7);
    const u16* src = ((slot < 8) ? hi : lo) + base + (long)col * kstride + 8 * chunk;
    gload_lds16(src, sbuf + i * 512);
  }
}

__device__ __forceinline__ bf16x8 rdfrag(const u16* sbuf, int col, int chunk, int c7, int lo) {
  const int slot = (chunk ^ c7) + (lo << 3);
  return *(const bf16x8*)(sbuf + col * 128 + slot * 8);
}

// ---- detector: flags[0]=1 if float inputs are f32; flags[1]=1 if mask is byte ----
__global__ void detect_kernel(const u16* __restrict__ G,
                              const u8* __restrict__ mask,
                              int* __restrict__ flags) {
  __shared__ int sf[2];
  const int t = threadIdx.x;
  if (t < 2) sf[t] = 0;
  __syncthreads();
  int isf = 0;
  for (int i = t; i < 256; i += 256) {
    int e = (G[2 * i] >> 7) & 0xff;
    if (e >= 150) isf = 1;
  }
  int mb = 0;
  for (int i = t; i < 4096; i += 256) {
    if (i && (i & 3) && mask[i]) mb = 1;
  }
  if (isf) atomicOr(&sf[0], 1);
  if (mb) atomicOr(&sf[1], 1);
  __syncthreads();
  if (t < 2) flags[t] = sf[t];
}

// ---- prep: transpose + hi/lo bf16-split weights into workspace ----
__global__ void prep_kernel(const void* __restrict__ in_w, const void* __restrict__ out_w,
                            u16* __restrict__ wt_hi, u16* __restrict__ wt_lo,
                            u16* __restrict__ ow_hi, u16* __restrict__ ow_lo,
                            const int* __restrict__ flags) {
  const bool f32 = flags[0] != 0;
  const int i = blockIdx.x * blockDim.x + threadIdx.x;
  if (i < LAYERS * F3 * ED) {
    const int l = i / (F3 * ED);
    const int rem = i % (F3 * ED);
    const int f = rem / ED;
    const int e = rem % ED;
    const long src = (long)(l * ED + e) * F3 + f;
    const float w = f32 ? ((const float*)in_w)[src] : bf2f(((const u16*)in_w)[src]);
    const u16 h = f2bf(w);
    wt_hi[i] = h;
    wt_lo[i] = f2bf(w - bf2f(h));
  }
  if (i < LAYERS * ED * HD) {
    const int l = i / (ED * HD);
    const int rem = i % (ED * HD);
    const int e = rem / HD;
    const int hh = rem % HD;
    const long src = (long)(l * HD + hh) * ED + e;
    const float w = f32 ? ((const float*)out_w)[src] : bf2f(((const u16*)out_w)[src]);
    const u16 h = f2bf(w);
    ow_hi[i] = h;
    ow_lo[i] = f2bf(w - bf2f(h));
  }
}

__global__ __launch_bounds__(T, 2) void nwa_kernel(
    const void* __restrict__ G, const void* __restrict__ mask,
    const void* __restrict__ rr,
    const void* __restrict__ in_b, const void* __restrict__ out_b,
    const void* __restrict__ ln_g, const void* __restrict__ ln_b,
    const u16* __restrict__ wt_hi, const u16* __restrict__ wt_lo,
    const u16* __restrict__ ow_hi, const u16* __restrict__ ow_lo,
    void* __restrict__ out, const int* __restrict__ flags)
{
  const bool f32f = flags[0] != 0;
  const bool mbyte = flags[1] != 0;

  __shared__ __align__(16) u16 x_hi[NPAD][XP];     // x residual, bf16 hi
  __shared__ __align__(16) u16 x_lo[NPAD][XP];     // x residual, bf16 lo
  __shared__ __align__(16) u16 q_s[NPAD][QPAD];    // weight staging (2x16KB) / q / aw / o
  __shared__ __align__(16) u16 k_s[NPAD][QPAD];    // k
  __shared__ __align__(16) u16 vT_s[HD][QPAD];     // v transposed [h][m]
  __shared__ __align__(16) float r_s[NPAD][4];
  __shared__ int m_s[NPAD];

  const int b = blockIdx.x;
  const int t = threadIdx.x;
  const int wave = t >> 6;
  const int lane = t & 63;
  const int g = lane >> 4;
  const int c = lane & 15;
  const int c7 = c & 7;
  u16* sbase = &q_s[0][0];   // staging area: 2 x 8192 u16 = 32 KB (q_s is 34.8 KB)

  // ---- load x (split hi/lo), r, mask; zero pads ----
  {
    const long gbase = (long)b * (NNEI * ED);
    for (int i = t; i < NNEI * ED; i += T) {
      const int rrow = i >> 6, cc = i & 63;
      if (f32f) {
        const float v = ((const float*)G)[gbase + i];
        const u16 h = f2bf(v);
        x_hi[rrow][cc] = h;
        x_lo[rrow][cc] = f2bf(v - bf2f(h));
      } else {
        x_hi[rrow][cc] = ((const u16*)G)[gbase + i];
        x_lo[rrow][cc] = 0;
      }
    }
    for (int i = t; i < (NPAD - NNEI) * ED; i += T) {
      x_hi[NNEI + (i >> 6)][i & 63] = 0;
      x_lo[NNEI + (i >> 6)][i & 63] = 0;
    }
    const long rbase = (long)b * (NNEI * 3);
    const long mbase = (long)b * NNEI;
    for (int i = t; i < NPAD; i += T) {
      if (i < NNEI) {
        r_s[i][0] = gldr(rr, rbase + i * 3 + 0, f32f);
        r_s[i][1] = gldr(rr, rbase + i * 3 + 1, f32f);
        r_s[i][2] = gldr(rr, rbase + i * 3 + 2, f32f);
        r_s[i][3] = 0.f;
        m_s[i] = mbyte ? (int)((const u8*)mask)[mbase + i] : ((const int*)mask)[mbase + i];
      } else {
        r_s[i][0] = 0.f; r_s[i][1] = 0.f; r_s[i][2] = 0.f; r_s[i][3] = 0.f;
        m_s[i] = 0;
      }
    }
  }
  __syncthreads();

  int vmask = 0;
  #pragma unroll
  for (int mt = 0; mt < 8; ++mt) vmask |= (m_s[16 * mt + c] ? 1 : 0) << mt;
  float qmr[4];
  #pragma unroll
  for (int r = 0; r < 4; ++r) qmr[r] = m_s[16 * wave + 4 * g + r] ? 1.f : 0.f;

  for (int l = 0; l < LAYERS; ++l) {
    const long wofs = (long)l * (F3 * ED);
    const long bbase = (long)l * F3;
    const long oofs = (long)l * (ED * HD);

    // ---- phase 1: qkv = x @ in_w, staged weights, acc in registers ----
    bf16x8 a_hi[2], a_lo[2];
    #pragma unroll
    for (int kf = 0; kf < 2; ++kf) {
      a_hi[kf] = *(const bf16x8*)&x_hi[16 * wave + c][32 * kf + 8 * g];
      a_lo[kf] = *(const bf16x8*)&x_lo[16 * wave + c][32 * kf + 8 * g];
    }
    f32x4 accQ[8], accB[8];
    #pragma unroll
    for (int i2 = 0; i2 < 8; ++i2) { accQ[i2] = (f32x4){0,0,0,0}; accB[i2] = (f32x4){0,0,0,0}; }

    // stage order: k,k,v,v,q,q  (natural tile n = (ss+2)%6, fbase = 64n)
    stage16(wt_hi, wt_lo, wofs + (long)2 * 64 * 64, 64, sbase, wave, lane);
    __syncthreads();

    #pragma unroll
    for (int ss = 0; ss < 6; ++ss) {
      const int n = (ss + 2) % 6;
      if (ss < 5) {
        const int nn = (ss + 3) % 6;
        stage16(wt_hi, wt_lo, wofs + (long)nn * 64 * 64, 64,
                sbase + ((ss + 1) & 1) * 8192, wave, lane);
      }
      const u16* sb = sbase + (ss & 1) * 8192;
      const bool isQ = (n < 2);
      #pragma unroll
      for (int ct = 0; ct < 4; ++ct) {
        const int tt = 4 * n + ct;
        const int nt = tt & 7;
        const int col = 16 * ct + c;
        const bf16x8 bh0 = rdfrag(sb, col, g, c7, 0);
        const bf16x8 bh1 = rdfrag(sb, col, 4 + g, c7, 0);
        const bf16x8 bl0 = rdfrag(sb, col, g, c7, 1);
        const bf16x8 bl1 = rdfrag(sb, col, 4 + g, c7, 1);
        f32x4 d = isQ ? accQ[nt] : accB[nt];
        MFMA(a_hi[0], bh0, d); MFMA(a_hi[1], bh1, d);
        MFMA(a_lo[0], bh0, d); MFMA(a_lo[1], bh1, d);
        MFMA(a_hi[0], bl0, d); MFMA(a_hi[1], bl1, d);
        if (isQ) accQ[nt] = d; else accB[nt] = d;
      }
      if (ss == 1) {          // K complete: bias + l2norm + store to k_s; reset accB
        float invr[4];
        #pragma unroll
        for (int nt = 0; nt < 8; ++nt) {
          const float bias = gldr(in_b, bbase + 128 + 16 * nt + c, f32f);
          accB[nt][0] += bias; accB[nt][1] += bias; accB[nt][2] += bias; accB[nt][3] += bias;
        }
        #pragma unroll
        for (int r = 0; r < 4; ++r) {
          float ssum = 0.f;
          #pragma unroll
          for (int nt = 0; nt < 8; ++nt) ssum += accB[nt][r] * accB[nt][r];
          ssum = red16sum(ssum);
          invr[r] = 1.f / fmaxf(sqrtf(ssum), 1e-12f);
        }
        #pragma unroll
        for (int nt = 0; nt < 8; ++nt) {
          #pragma unroll
          for (int r = 0; r < 4; ++r)
            k_s[16 * wave + 4 * g + r][16 * nt + c] = f2bf(accB[nt][r] * invr[r]);
          accB[nt] = (f32x4){0,0,0,0};
        }
      } else if (ss == 3) {   // V complete: bias + l2norm + store transposed to vT_s
        float invr[4];
        #pragma unroll
        for (int nt = 0; nt < 8; ++nt) {
          const float bias = gldr(in_b, bbase + 256 + 16 * nt + c, f32f);
          accB[nt][0] += bias; accB[nt][1] += bias; accB[nt][2] += bias; accB[nt][3] += bias;
        }
        #pragma unroll
        for (int r = 0; r < 4; ++r) {
          float ssum = 0.f;
          #pragma unroll
          for (int nt = 0; nt < 8; ++nt) ssum += accB[nt][r] * accB[nt][r];
          ssum = red16sum(ssum);
          invr[r] = 1.f / fmaxf(sqrtf(ssum), 1e-12f);
        }
        #pragma unroll
        for (int nt = 0; nt < 8; ++nt) {
          const u32 p01 = (u32)f2bf(accB[nt][0] * invr[0]) | ((u32)f2bf(accB[nt][1] * invr[1]) << 16);
          const u32 p23 = (u32)f2bf(accB[nt][2] * invr[2]) | ((u32)f2bf(accB[nt][3] * invr[3]) << 16);
          *(u32*)&vT_s[16 * nt + c][16 * wave + 4 * g + 0] = p01;
          *(u32*)&vT_s[16 * nt + c][16 * wave + 4 * g + 2] = p23;
        }
      }
      __syncthreads();
    }
    {   // Q complete: bias + l2norm*SCALING + store to q_s (staging now dead)
      float invr[4];
      #pragma unroll
      for (int nt = 0; nt < 8; ++nt) {
        const float bias = gldr(in_b, bbase + 16 * nt + c, f32f);
        accQ[nt][0] += bias; accQ[nt][1] += bias; accQ[nt][2] += bias; accQ[nt][3] += bias;
      }
      #pragma unroll
      for (int r = 0; r < 4; ++r) {
        float ssum = 0.f;
        #pragma unroll
        for (int nt = 0; nt < 8; ++nt) ssum += accQ[nt][r] * accQ[nt][r];
        ssum = red16sum(ssum);
        invr[r] = SCALING / fmaxf(sqrtf(ssum), 1e-12f);
      }
      #pragma unroll
      for (int nt = 0; nt < 8; ++nt)
        #pragma unroll
        for (int r = 0; r < 4; ++r)
          q_s[16 * wave + 4 * g + r][16 * nt + c] = f2bf(accQ[nt][r] * invr[r]);
    }
    // No barrier: q/aw/o in q_s are per-wave-band; k_s/vT_s writes were
    // barrier-covered by the stage-loop syncthreads. Waves drift freely here.

    // ---- QK^T ----
    f32x4 s[8];
    {
      bf16x8 aq[4];
      #pragma unroll
      for (int kf = 0; kf < 4; ++kf)
        aq[kf] = *(const bf16x8*)&q_s[16 * wave + c][32 * kf + 8 * g];
      #pragma unroll
      for (int mt = 0; mt < 8; ++mt) {
        const u16* kp = &k_s[16 * mt + c][8 * g];
        f32x4 d = {0.f, 0.f, 0.f, 0.f};
        #pragma unroll
        for (int kf = 0; kf < 4; ++kf)
          MFMA(aq[kf], *(const bf16x8*)(kp + 32 * kf), d);
        s[mt] = d;
      }
    }

    // ---- softmax + mask_q + ang; aw -> q_s (own band) ----
    {
      const f32x4 minf = {-INFINITY, -INFINITY, -INFINITY, -INFINITY};
      #pragma unroll
      for (int mt = 0; mt < 8; ++mt)
        if (!((vmask >> mt) & 1)) s[mt] = minf;
      float inv[4];
      float4 rnr[4];
      #pragma unroll
      for (int r = 0; r < 4; ++r) {
        float mx = s[0][r];
        #pragma unroll
        for (int mt = 1; mt < 8; ++mt) mx = fmaxf(mx, s[mt][r]);
        mx = red16max(mx);
        float sm = 0.f;
        #pragma unroll
        for (int mt = 0; mt < 8; ++mt) {
          const float e = __expf(s[mt][r] - mx);
          s[mt][r] = e;
          sm += e;
        }
        sm = red16sum(sm);
        inv[r] = qmr[r] / sm;
        rnr[r] = *(const float4*)&r_s[16 * wave + 4 * g + r][0];
      }
      #pragma unroll
      for (int mt = 0; mt < 8; ++mt) {
        const float4 rm = *(const float4*)&r_s[16 * mt + c][0];
        #pragma unroll
        for (int r = 0; r < 4; ++r) {
          const float w = s[mt][r] * inv[r] *
              (rnr[r].x * rm.x + rnr[r].y * rm.y + rnr[r].z * rm.z);
          q_s[16 * wave + 4 * g + r][16 * mt + c] = f2bf(w);
        }
      }
    }

    // ---- PV (o = aw @ v); o overwrites aw in q_s own band ----
    {
      bf16x8 pa[4];
      #pragma unroll
      for (int kf = 0; kf < 4; ++kf)
        pa[kf] = *(const bf16x8*)&q_s[16 * wave + c][32 * kf + 8 * g];
      f32x4 o[8];
      #pragma unroll
      for (int ht = 0; ht < 8; ++ht) {
        const u16* vp = &vT_s[16 * ht + c][8 * g];
        f32x4 d = {0.f, 0.f, 0.f, 0.f};
        #pragma unroll
        for (int kf = 0; kf < 4; ++kf)
          MFMA(pa[kf], *(const bf16x8*)(vp + 32 * kf), d);
        o[ht] = d;
      }
      #pragma unroll
      for (int ht = 0; ht < 8; ++ht)
        #pragma unroll
        for (int r = 0; r < 4; ++r)
          q_s[16 * wave + 4 * g + r][16 * ht + c] = f2bf(o[ht][r]);
    }

    // ---- phase 4: x = LN(residual + o @ out_w + out_b), staged out_w ----
    bf16x8 ao[4];
    #pragma unroll
    for (int kf = 0; kf < 4; ++kf)
      ao[kf] = *(const bf16x8*)&q_s[16 * wave + c][32 * kf + 8 * g];
    __syncthreads();   // barrier D: all waves done with q_s before ow staging reuses it
    stage16(ow_hi, ow_lo, oofs, 128, sbase, wave, lane);        // h-half 0
    __syncthreads();
    f32x4 dv[4];
    #pragma unroll
    for (int nt = 0; nt < 4; ++nt) dv[nt] = (f32x4){0,0,0,0};
    #pragma unroll
    for (int kh = 0; kh < 2; ++kh) {
      if (kh == 0) stage16(ow_hi, ow_lo, oofs + 64, 128, sbase + 8192, wave, lane);
      const u16* sb = sbase + kh * 8192;
      #pragma unroll
      for (int nt = 0; nt < 4; ++nt) {
        const int col = 16 * nt + c;
        #pragma unroll
        for (int kfl = 0; kfl < 2; ++kfl) {
          const bf16x8 bh = rdfrag(sb, col, 4 * kfl + g, c7, 0);
          const bf16x8 bl = rdfrag(sb, col, 4 * kfl + g, c7, 1);
          f32x4 d2 = dv[nt];
          MFMA(ao[2 * kh + kfl], bh, d2);
          MFMA(ao[2 * kh + kfl], bl, d2);
          dv[nt] = d2;
        }
      }
      if (kh == 0) __syncthreads();
    }
    {
      float gg[4], bbv[4];
      #pragma unroll
      for (int nt = 0; nt < 4; ++nt) {
        const int e = 16 * nt + c;
        const float ob = gldr(out_b, (long)l * ED + e, f32f);
        gg[nt]  = gldr(ln_g, (long)l * ED + e, f32f);
        bbv[nt] = gldr(ln_b, (long)l * ED + e, f32f);
        #pragma unroll
        for (int r = 0; r < 4; ++r) {
          const int n = 16 * wave + 4 * g + r;
          dv[nt][r] += ob + bf2f(x_hi[n][e]) + bf2f(x_lo[n][e]);
        }
      }
      #pragma unroll
      for (int r = 0; r < 4; ++r) {
        const int n = 16 * wave + 4 * g + r;
        float mu = dv[0][r] + dv[1][r] + dv[2][r] + dv[3][r];
        mu = red16sum(mu) * (1.f / 64.f);
        float var = 0.f;
        #pragma unroll
        for (int nt = 0; nt < 4; ++nt) { const float dd = dv[nt][r] - mu; var += dd * dd; }
        var = red16sum(var) * (1.f / 64.f);
        const float rs = rsqrtf(var + LN_EPS);
        if (n < NNEI) {
          #pragma unroll
          for (int nt = 0; nt < 4; ++nt) {
            const float y = (dv[nt][r] - mu) * rs * gg[nt] + bbv[nt];
            const u16 hh = f2bf(y);
            x_hi[n][16 * nt + c] = hh;
            x_lo[n][16 * nt + c] = f2bf(y - bf2f(hh));
            if (l == LAYERS - 1) {
              const long oidx = (long)b * (NNEI * ED) + (long)n * ED + 16 * nt + c;
              if (f32f) ((float*)out)[oidx] = y;
              else      ((u16*)out)[oidx] = f2bf(y);
            }
          }
        }
      }
    }
    // next layer's prologue syncthreads covers staging-buffer reuse
  }
}

extern "C" void kernel_launch(void* const* d_in, const int* in_sizes, int n_in,
                              void* d_out, int out_size, void* d_ws, size_t ws_size,
                              hipStream_t stream) {
  (void)in_sizes; (void)n_in; (void)out_size; (void)ws_size;
  const void* G = d_in[0];
  const void* mask = d_in[1];
  const void* rr = d_in[2];
  const void* in_w = d_in[3];
  const void* in_b = d_in[4];
  const void* out_w = d_in[5];
  const void* out_b = d_in[6];
  const void* ln_g = d_in[7];
  const void* ln_b = d_in[8];

  int* flags = (int*)d_ws;
  u16* wt_hi = (u16*)((char*)d_ws + 256);
  u16* wt_lo = wt_hi + LAYERS * F3 * ED;
  u16* ow_hi = wt_lo + LAYERS * F3 * ED;
  u16* ow_lo = ow_hi + LAYERS * ED * HD;

  detect_kernel<<<dim3(1), dim3(256), 0, stream>>>((const u16*)G, (const u8*)mask, flags);
  prep_kernel<<<dim3(96), dim3(T), 0, stream>>>(in_w, out_w, wt_hi, wt_lo, ow_hi, ow_lo, flags);
  nwa_kernel<<<dim3(NB), dim3(T), 0, stream>>>(
      G, mask, rr, in_b, out_b, ln_g, ln_b, wt_hi, wt_lo, ow_hi, ow_lo, d_out, flags);
}

// Round 3
// 846.973 us; speedup vs baseline: 6.6701x; 1.0591x over previous
//
#include <hip/hip_runtime.h>
#include <math.h>

#define LAYERS 2
#define NNEI 120
#define NPAD 128
#define ED 64
#define HD 128
#define NB 4096
#define F3 (3*HD)
#define SCALING 0.088388347648318447f
#define LN_EPS 1e-5f
#define T 1024
#define XP 72
#define QPAD 136

typedef unsigned short u16;
typedef unsigned int u32;
typedef unsigned char u8;
typedef float f32x4 __attribute__((ext_vector_type(4)));
typedef short bf16x8 __attribute__((ext_vector_type(8)));

__device__ __forceinline__ float bf2f(u16 u) { return __uint_as_float(((u32)u) << 16); }
__device__ __forceinline__ u16 f2bf(float f) {
  __bf16 b = (__bf16)f;                       // HW RNE convert (v_cvt_pk_bf16_f32)
  return __builtin_bit_cast(u16, b);
}
__device__ __forceinline__ u32 pk2bf(float lo, float hi) {
  return (u32)f2bf(lo) | ((u32)f2bf(hi) << 16);
}
__device__ __forceinline__ float gldr(const void* p, long i, bool f32) {
  return f32 ? ((const float*)p)[i] : bf2f(((const u16*)p)[i]);
}
__device__ __forceinline__ float red16sum(float v) {
  v += __shfl_xor(v, 1); v += __shfl_xor(v, 2);
  v += __shfl_xor(v, 4); v += __shfl_xor(v, 8);
  return v;
}

#define MFMA(a, b, d) (d) = __builtin_amdgcn_mfma_f32_16x16x32_bf16((a), (b), (d), 0, 0, 0)

__device__ __forceinline__ void gload_lds16(const u16* src, u16* dst) {
  __builtin_amdgcn_global_load_lds(
      (const __attribute__((address_space(1))) u32*)(const void*)src,
      (__attribute__((address_space(3))) u32*)(void*)dst, 16, 0, 0);
}

// Stage a [64 col][64 k] hi+lo weight tile (16 KB) into sbuf (one instr/wave,
// 16 waves). LDS: row=col (256B = 16 slots of 16B); slots 0..7 = hi k-chunks,
// 8..15 = lo; stored slot s holds chunk (s&7)^(col&7) (involution).
__device__ __forceinline__ void stage16(const u16* __restrict__ hi, const u16* __restrict__ lo,
                                        long base, int kstride, u16* sbuf, int wave, int lane) {
  const int col = 4 * wave + (lane >> 4);
  const int slot = lane & 15;
  const int chunk = (slot & 7) ^ (col & 7);
  const u16* src = ((slot < 8) ? hi : lo) + base + (long)col * kstride + 8 * chunk;
  gload_lds16(src, sbuf + wave * 512);
}

__device__ __forceinline__ bf16x8 rdfrag(const u16* sbuf, int col, int chunk, int c7, int lo) {
  const int slot = (chunk ^ c7) + (lo << 3);
  return *(const bf16x8*)(sbuf + col * 128 + slot * 8);
}

// ---- detector: flags[0]=1 if float inputs are f32; flags[1]=1 if mask is byte ----
__global__ void detect_kernel(const u16* __restrict__ G,
                              const u8* __restrict__ mask,
                              int* __restrict__ flags) {
  __shared__ int sf[2];
  const int t = threadIdx.x;
  if (t < 2) sf[t] = 0;
  __syncthreads();
  int isf = 0;
  for (int i = t; i < 256; i += 256) {
    int e = (G[2 * i] >> 7) & 0xff;
    if (e >= 150) isf = 1;
  }
  int mb = 0;
  for (int i = t; i < 4096; i += 256) {
    if (i && (i & 3) && mask[i]) mb = 1;
  }
  if (isf) atomicOr(&sf[0], 1);
  if (mb) atomicOr(&sf[1], 1);
  __syncthreads();
  if (t < 2) flags[t] = sf[t];
}

// ---- prep: transpose + hi/lo bf16-split weights into workspace ----
__global__ void prep_kernel(const void* __restrict__ in_w, const void* __restrict__ out_w,
                            u16* __restrict__ wt_hi, u16* __restrict__ wt_lo,
                            u16* __restrict__ ow_hi, u16* __restrict__ ow_lo,
                            const int* __restrict__ flags) {
  const bool f32 = flags[0] != 0;
  const int i = blockIdx.x * blockDim.x + threadIdx.x;
  if (i < LAYERS * F3 * ED) {
    const int l = i / (F3 * ED);
    const int rem = i % (F3 * ED);
    const int f = rem / ED;
    const int e = rem % ED;
    const long src = (long)(l * ED + e) * F3 + f;
    const float w = f32 ? ((const float*)in_w)[src] : bf2f(((const u16*)in_w)[src]);
    const u16 h = f2bf(w);
    wt_hi[i] = h;
    wt_lo[i] = f2bf(w - bf2f(h));
  }
  if (i < LAYERS * ED * HD) {
    const int l = i / (ED * HD);
    const int rem = i % (ED * HD);
    const int e = rem / HD;
    const int hh = rem % HD;
    const long src = (long)(l * HD + hh) * ED + e;
    const float w = f32 ? ((const float*)out_w)[src] : bf2f(((const u16*)out_w)[src]);
    const u16 h = f2bf(w);
    ow_hi[i] = h;
    ow_lo[i] = f2bf(w - bf2f(h));
  }
}

__global__ __launch_bounds__(T) void nwa_kernel(
    const void* __restrict__ G, const void* __restrict__ mask,
    const void* __restrict__ rr,
    const void* __restrict__ in_b, const void* __restrict__ out_b,
    const void* __restrict__ ln_g, const void* __restrict__ ln_b,
    const u16* __restrict__ wt_hi, const u16* __restrict__ wt_lo,
    const u16* __restrict__ ow_hi, const u16* __restrict__ ow_lo,
    void* __restrict__ out, const int* __restrict__ flags)
{
  const bool f32f = flags[0] != 0;
  const bool mbyte = flags[1] != 0;

  __shared__ __align__(16) u16 x_hi[NPAD][XP];     // x residual, bf16 hi
  __shared__ __align__(16) u16 x_lo[NPAD][XP];     // x residual, bf16 lo
  __shared__ __align__(16) u16 q_s[NPAD][QPAD];    // weight staging (2x16KB) / q / aw
  __shared__ __align__(16) u16 k_s[NPAD][QPAD];    // k, then o
  __shared__ __align__(16) u16 vT_s[HD][QPAD];     // v transposed [h][m]
  __shared__ __align__(16) float r_s[NPAD][4];
  __shared__ __align__(16) float pA[2][8][16];     // cross-half reduce scratch
  __shared__ __align__(16) float pB[2][8][16];
  __shared__ int m_s[NPAD];

  const int b = blockIdx.x;
  const int t = threadIdx.x;
  const int wave = t >> 6;
  const int band = wave & 7;     // 16-row band
  const int half = wave >> 3;    // column/k-tile half
  const int lane = t & 63;
  const int g = lane >> 4;
  const int c = lane & 15;
  const int c7 = c & 7;
  u16* sbase = &q_s[0][0];       // staging: 2 x 8192 u16 = 32 KB

  // ---- load x (split hi/lo), r, mask; zero pads ----
  {
    const long gbase = (long)b * (NNEI * ED);
    for (int i = t; i < NNEI * ED; i += T) {
      const int rrow = i >> 6, cc = i & 63;
      if (f32f) {
        const float v = ((const float*)G)[gbase + i];
        const u16 h = f2bf(v);
        x_hi[rrow][cc] = h;
        x_lo[rrow][cc] = f2bf(v - bf2f(h));
      } else {
        x_hi[rrow][cc] = ((const u16*)G)[gbase + i];
        x_lo[rrow][cc] = 0;
      }
    }
    for (int i = t; i < (NPAD - NNEI) * ED; i += T) {
      x_hi[NNEI + (i >> 6)][i & 63] = 0;
      x_lo[NNEI + (i >> 6)][i & 63] = 0;
    }
    const long rbase = (long)b * (NNEI * 3);
    const long mbase = (long)b * NNEI;
    for (int i = t; i < NPAD; i += T) {
      if (i < NNEI) {
        r_s[i][0] = gldr(rr, rbase + i * 3 + 0, f32f);
        r_s[i][1] = gldr(rr, rbase + i * 3 + 1, f32f);
        r_s[i][2] = gldr(rr, rbase + i * 3 + 2, f32f);
        r_s[i][3] = 0.f;
        m_s[i] = mbyte ? (int)((const u8*)mask)[mbase + i] : ((const int*)mask)[mbase + i];
      } else {
        r_s[i][0] = 0.f; r_s[i][1] = 0.f; r_s[i][2] = 0.f; r_s[i][3] = 0.f;
        m_s[i] = 0;
      }
    }
  }
  stage16(wt_hi, wt_lo, (long)2 * 4096, 64, sbase, wave, lane);   // layer 0, K chunk 0
  __syncthreads();

  int vm[4];
  #pragma unroll
  for (int mtl = 0; mtl < 4; ++mtl) vm[mtl] = m_s[16 * (4 * half + mtl) + c];
  float qmr[4];
  #pragma unroll
  for (int r = 0; r < 4; ++r) qmr[r] = m_s[16 * band + 4 * g + r] ? 1.f : 0.f;

  for (int l = 0; l < LAYERS; ++l) {
    const long wofs = (long)l * (F3 * ED);
    const long bbase = (long)l * F3;
    const long oofs = (long)l * (ED * HD);
    const bool use_lo = f32f || (l > 0);   // x_lo == 0 for bf16 input at layer 0

    // ---- phase 1: qkv = x @ in_w (stage order K,K,V,V,Q,Q) ----
    bf16x8 a_hi[2], a_lo[2];
    #pragma unroll
    for (int kf = 0; kf < 2; ++kf) {
      a_hi[kf] = *(const bf16x8*)&x_hi[16 * band + c][32 * kf + 8 * g];
      a_lo[kf] = *(const bf16x8*)&x_lo[16 * band + c][32 * kf + 8 * g];
    }
    f32x4 accQ[4], accB[4];
    #pragma unroll
    for (int j = 0; j < 4; ++j) { accQ[j] = (f32x4){0,0,0,0}; accB[j] = (f32x4){0,0,0,0}; }

    #pragma unroll
    for (int ss = 0; ss < 6; ++ss) {
      const int n = (ss + 2) % 6;   // chunk: 2,3=K 4,5=V 0,1=Q
      if (ss < 5)
        stage16(wt_hi, wt_lo, wofs + (long)((ss + 3) % 6) * 4096, 64,
                sbase + ((ss + 1) & 1) * 8192, wave, lane);
      if (ss == 2) {   // K finalize: l2norm + store to k_s; reset accB
        const f32x4 sa = *(const f32x4*)&pA[0][band][4 * g];
        const f32x4 sb4 = *(const f32x4*)&pA[1][band][4 * g];
        float invr[4];
        #pragma unroll
        for (int r = 0; r < 4; ++r) invr[r] = rsqrtf(fmaxf(sa[r] + sb4[r], 1e-24f));
        #pragma unroll
        for (int j = 0; j < 4; ++j) {
          const int nt = 4 * (j >> 1) + 2 * half + (j & 1);
          #pragma unroll
          for (int r = 0; r < 4; ++r)
            k_s[16 * band + 4 * g + r][16 * nt + c] = f2bf(accB[j][r] * invr[r]);
          accB[j] = (f32x4){0,0,0,0};
        }
      }
      if (ss == 4) {   // V finalize: l2norm + store transposed to vT_s
        const f32x4 sa = *(const f32x4*)&pB[0][band][4 * g];
        const f32x4 sb4 = *(const f32x4*)&pB[1][band][4 * g];
        float invr[4];
        #pragma unroll
        for (int r = 0; r < 4; ++r) invr[r] = rsqrtf(fmaxf(sa[r] + sb4[r], 1e-24f));
        #pragma unroll
        for (int j = 0; j < 4; ++j) {
          const int nt = 4 * (j >> 1) + 2 * half + (j & 1);
          const u32 p01 = pk2bf(accB[j][0] * invr[0], accB[j][1] * invr[1]);
          const u32 p23 = pk2bf(accB[j][2] * invr[2], accB[j][3] * invr[3]);
          *(u32*)&vT_s[16 * nt + c][16 * band + 4 * g + 0] = p01;
          *(u32*)&vT_s[16 * nt + c][16 * band + 4 * g + 2] = p23;
        }
      }
      const u16* sb = sbase + (ss & 1) * 8192;
      #pragma unroll
      for (int ctl = 0; ctl < 2; ++ctl) {
        const int col = 16 * (2 * half + ctl) + c;
        const int j = 2 * (n & 1) + ctl;
        const bf16x8 bh0 = rdfrag(sb, col, g, c7, 0);
        const bf16x8 bh1 = rdfrag(sb, col, 4 + g, c7, 0);
        const bf16x8 bl0 = rdfrag(sb, col, g, c7, 1);
        const bf16x8 bl1 = rdfrag(sb, col, 4 + g, c7, 1);
        f32x4 d = (n < 2) ? accQ[j] : accB[j];
        MFMA(a_hi[0], bh0, d); MFMA(a_hi[1], bh1, d);
        if (use_lo) { MFMA(a_lo[0], bh0, d); MFMA(a_lo[1], bh1, d); }
        MFMA(a_hi[0], bl0, d); MFMA(a_hi[1], bl1, d);
        if (n < 2) accQ[j] = d; else accB[j] = d;
      }
      if (ss == 1 || ss == 3 || ss == 5) {   // bias + cross-half partial sum-of-squares
        const int fo = (ss == 1) ? 128 : (ss == 3) ? 256 : 0;
        f32x4* acc = (ss == 5) ? accQ : accB;
        #pragma unroll
        for (int j = 0; j < 4; ++j) {
          const int nt = 4 * (j >> 1) + 2 * half + (j & 1);
          const float bias = gldr(in_b, bbase + fo + 16 * nt + c, f32f);
          acc[j][0] += bias; acc[j][1] += bias; acc[j][2] += bias; acc[j][3] += bias;
        }
        float* dst = (ss == 3) ? &pB[half][band][0] : &pA[half][band][0];
        #pragma unroll
        for (int r = 0; r < 4; ++r) {
          const float ssum = acc[0][r] * acc[0][r] + acc[1][r] * acc[1][r] +
                             acc[2][r] * acc[2][r] + acc[3][r] * acc[3][r];
          const float red = red16sum(ssum);
          if (c == 0) dst[4 * g + r] = red;
        }
      }
      __syncthreads();
    }
    {   // Q finalize: l2norm * SCALING + store to q_s (staging dead)
      const f32x4 sa = *(const f32x4*)&pA[0][band][4 * g];
      const f32x4 sb4 = *(const f32x4*)&pA[1][band][4 * g];
      float invr[4];
      #pragma unroll
      for (int r = 0; r < 4; ++r) invr[r] = SCALING * rsqrtf(fmaxf(sa[r] + sb4[r], 1e-24f));
      #pragma unroll
      for (int j = 0; j < 4; ++j) {
        const int nt = 4 * (j >> 1) + 2 * half + (j & 1);
        #pragma unroll
        for (int r = 0; r < 4; ++r)
          q_s[16 * band + 4 * g + r][16 * nt + c] = f2bf(accQ[j][r] * invr[r]);
      }
    }
    __syncthreads();   // B2: q visible

    // ---- QK^T: 4 mt tiles per wave (half-split) ----
    f32x4 s4[4];
    {
      bf16x8 aq[4];
      #pragma unroll
      for (int kf = 0; kf < 4; ++kf)
        aq[kf] = *(const bf16x8*)&q_s[16 * band + c][32 * kf + 8 * g];
      #pragma unroll
      for (int mtl = 0; mtl < 4; ++mtl) {
        const u16* kp = &k_s[16 * (4 * half + mtl) + c][8 * g];
        f32x4 d = {0.f, 0.f, 0.f, 0.f};
        #pragma unroll
        for (int kf = 0; kf < 4; ++kf)
          MFMA(aq[kf], *(const bf16x8*)(kp + 32 * kf), d);
        s4[mtl] = d;
      }
    }
    // ---- softmax (no max pass: |logit| <= 0.089) ----
    {
      float psum[4] = {0.f, 0.f, 0.f, 0.f};
      #pragma unroll
      for (int mtl = 0; mtl < 4; ++mtl) {
        #pragma unroll
        for (int r = 0; r < 4; ++r) {
          const float e = vm[mtl] ? __expf(s4[mtl][r]) : 0.f;
          s4[mtl][r] = e;
          psum[r] += e;
        }
      }
      #pragma unroll
      for (int r = 0; r < 4; ++r) {
        const float red = red16sum(psum[r]);
        if (c == 0) pA[half][band][4 * g + r] = red;
      }
    }
    __syncthreads();   // F: denominators + vT_s published
    {
      const f32x4 sa = *(const f32x4*)&pA[0][band][4 * g];
      const f32x4 sb4 = *(const f32x4*)&pA[1][band][4 * g];
      float inv[4];
      f32x4 rn[4];
      #pragma unroll
      for (int r = 0; r < 4; ++r) {
        inv[r] = qmr[r] / (sa[r] + sb4[r]);
        rn[r] = *(const f32x4*)&r_s[16 * band + 4 * g + r][0];
      }
      #pragma unroll
      for (int mtl = 0; mtl < 4; ++mtl) {
        const int mt = 4 * half + mtl;
        const f32x4 rm = *(const f32x4*)&r_s[16 * mt + c][0];
        #pragma unroll
        for (int r = 0; r < 4; ++r) {
          const float w = s4[mtl][r] * inv[r] *
              (rn[r][0] * rm[0] + rn[r][1] * rm[1] + rn[r][2] * rm[2]);
          q_s[16 * band + 4 * g + r][16 * mt + c] = f2bf(w);
        }
      }
    }
    __syncthreads();   // G: aw visible

    // ---- PV: o -> k_s (free after QK^T) ----
    {
      bf16x8 pa[4];
      #pragma unroll
      for (int kf = 0; kf < 4; ++kf)
        pa[kf] = *(const bf16x8*)&q_s[16 * band + c][32 * kf + 8 * g];
      f32x4 o4[4];
      #pragma unroll
      for (int htl = 0; htl < 4; ++htl) {
        const u16* vp = &vT_s[16 * (4 * half + htl) + c][8 * g];
        f32x4 d = {0.f, 0.f, 0.f, 0.f};
        #pragma unroll
        for (int kf = 0; kf < 4; ++kf)
          MFMA(pa[kf], *(const bf16x8*)(vp + 32 * kf), d);
        o4[htl] = d;
      }
      #pragma unroll
      for (int htl = 0; htl < 4; ++htl)
        #pragma unroll
        for (int r = 0; r < 4; ++r)
          k_s[16 * band + 4 * g + r][16 * (4 * half + htl) + c] = f2bf(o4[htl][r]);
    }
    __syncthreads();   // H: o visible; q_s free for staging

    // ---- phase 4: x = LN(residual + o @ out_w + out_b) ----
    bf16x8 ao[4];
    #pragma unroll
    for (int kf = 0; kf < 4; ++kf)
      ao[kf] = *(const bf16x8*)&k_s[16 * band + c][32 * kf + 8 * g];
    stage16(ow_hi, ow_lo, oofs, 128, sbase, wave, lane);        // h-half 0
    __syncthreads();   // S1
    f32x4 dv[2];
    dv[0] = (f32x4){0,0,0,0}; dv[1] = (f32x4){0,0,0,0};
    #pragma unroll
    for (int kh = 0; kh < 2; ++kh) {
      if (kh == 0) stage16(ow_hi, ow_lo, oofs + 64, 128, sbase + 8192, wave, lane);
      const u16* sb = sbase + kh * 8192;
      #pragma unroll
      for (int ntl = 0; ntl < 2; ++ntl) {
        const int col = 16 * (2 * half + ntl) + c;
        #pragma unroll
        for (int kfl = 0; kfl < 2; ++kfl) {
          const bf16x8 bh = rdfrag(sb, col, 4 * kfl + g, c7, 0);
          const bf16x8 bl = rdfrag(sb, col, 4 * kfl + g, c7, 1);
          MFMA(ao[2 * kh + kfl], bh, dv[ntl]);
          MFMA(ao[2 * kh + kfl], bl, dv[ntl]);
        }
      }
      if (kh == 0) __syncthreads();   // S2
    }
    if (l + 1 < LAYERS)   // prefetch next layer's first weight chunk (buffer0 free)
      stage16(wt_hi, wt_lo, (long)(l + 1) * (F3 * ED) + (long)2 * 4096, 64, sbase, wave, lane);
    {
      #pragma unroll
      for (int ntl = 0; ntl < 2; ++ntl) {
        const int e0 = 16 * (2 * half + ntl) + c;
        const float ob = gldr(out_b, (long)l * ED + e0, f32f);
        #pragma unroll
        for (int r = 0; r < 4; ++r) {
          const int nrow = 16 * band + 4 * g + r;
          dv[ntl][r] += ob + bf2f(x_hi[nrow][e0]) + bf2f(x_lo[nrow][e0]);
        }
      }
      #pragma unroll
      for (int r = 0; r < 4; ++r) {
        const float sx = red16sum(dv[0][r] + dv[1][r]);
        const float sxx = red16sum(dv[0][r] * dv[0][r] + dv[1][r] * dv[1][r]);
        if (c == 0) { pA[half][band][4 * g + r] = sx; pB[half][band][4 * g + r] = sxx; }
      }
    }
    __syncthreads();   // I
    {
      const f32x4 xa = *(const f32x4*)&pA[0][band][4 * g];
      const f32x4 xb = *(const f32x4*)&pA[1][band][4 * g];
      const f32x4 ya = *(const f32x4*)&pB[0][band][4 * g];
      const f32x4 yb = *(const f32x4*)&pB[1][band][4 * g];
      float gg[2], bbv[2];
      #pragma unroll
      for (int ntl = 0; ntl < 2; ++ntl) {
        const int e0 = 16 * (2 * half + ntl) + c;
        gg[ntl]  = gldr(ln_g, (long)l * ED + e0, f32f);
        bbv[ntl] = gldr(ln_b, (long)l * ED + e0, f32f);
      }
      #pragma unroll
      for (int r = 0; r < 4; ++r) {
        const int nrow = 16 * band + 4 * g + r;
        const float mu = (xa[r] + xb[r]) * (1.f / 64.f);
        const float ex2 = (ya[r] + yb[r]) * (1.f / 64.f);
        const float rs = rsqrtf(fmaxf(ex2 - mu * mu, 0.f) + LN_EPS);
        if (nrow < NNEI) {
          #pragma unroll
          for (int ntl = 0; ntl < 2; ++ntl) {
            const int e0 = 16 * (2 * half + ntl) + c;
            const float y = (dv[ntl][r] - mu) * rs * gg[ntl] + bbv[ntl];
            if (l + 1 < LAYERS) {
              const u16 hh2 = f2bf(y);
              x_hi[nrow][e0] = hh2;
              x_lo[nrow][e0] = f2bf(y - bf2f(hh2));
            } else {
              const long oidx = (long)b * (NNEI * ED) + (long)nrow * ED + e0;
              if (f32f) ((float*)out)[oidx] = y;
              else      ((u16*)out)[oidx] = f2bf(y);
            }
          }
        }
      }
    }
    if (l + 1 < LAYERS) __syncthreads();   // P: x + stage0 ready
  }
}

extern "C" void kernel_launch(void* const* d_in, const int* in_sizes, int n_in,
                              void* d_out, int out_size, void* d_ws, size_t ws_size,
                              hipStream_t stream) {
  (void)in_sizes; (void)n_in; (void)out_size; (void)ws_size;
  const void* G = d_in[0];
  const void* mask = d_in[1];
  const void* rr = d_in[2];
  const void* in_w = d_in[3];
  const void* in_b = d_in[4];
  const void* out_w = d_in[5];
  const void* out_b = d_in[6];
  const void* ln_g = d_in[7];
  const void* ln_b = d_in[8];

  int* flags = (int*)d_ws;
  u16* wt_hi = (u16*)((char*)d_ws + 256);
  u16* wt_lo = wt_hi + LAYERS * F3 * ED;
  u16* ow_hi = wt_lo + LAYERS * F3 * ED;
  u16* ow_lo = ow_hi + LAYERS * ED * HD;

  detect_kernel<<<dim3(1), dim3(256), 0, stream>>>((const u16*)G, (const u8*)mask, flags);
  prep_kernel<<<dim3(96), dim3(512), 0, stream>>>(in_w, out_w, wt_hi, wt_lo, ow_hi, ow_lo, flags);
  nwa_kernel<<<dim3(NB), dim3(T), 0, stream>>>(
      G, mask, rr, in_b, out_b, ln_g, ln_b, wt_hi, wt_lo, ow_hi, ow_lo, d_out, flags);
}